// Round 1
// baseline (395.695 us; speedup 1.0000x reference)
//
#include <hip/hip_runtime.h>
#include <math.h>

#define D      128
#define S_LEN  64
#define B_SZ   512
#define NH     4
#define DH     32
#define NB     2
#define VOCAB  9
#define EPS    1e-5f
#define NTOK   (B_SZ * S_LEN)

// ---------------- DPP helpers (ctrl must be compile-time constant) ----------
template <int CTRL>
__device__ __forceinline__ float dppf(float x) {
    return __int_as_float(__builtin_amdgcn_update_dpp(
        0, __float_as_int(x), CTRL, 0xF, 0xF, true));
}
// wave64 sum -> wave-uniform scalar (canonical row_shr/bcast sequence)
__device__ __forceinline__ float wsum64(float x) {
    x += dppf<0x111>(x);  // row_shr:1
    x += dppf<0x112>(x);  // row_shr:2
    x += dppf<0x114>(x);  // row_shr:4
    x += dppf<0x118>(x);  // row_shr:8
    x += dppf<0x142>(x);  // row_bcast:15
    x += dppf<0x143>(x);  // row_bcast:31
    return __int_as_float(__builtin_amdgcn_readlane(__float_as_int(x), 63));
}

// LDS swizzles (all xor bits>=2 -> float4 alignment preserved)
__device__ __forceinline__ int xg (int c)        { return c ^ ((c >> 5) << 3); }

// async global->LDS, 16B/lane. LDS dest is wave-uniform base + lane*16
// (m104); per-lane GLOBAL address is free, which is how the XOR swizzle
// is applied (rule #21: pre-swizzled source + swizzled read, linear dest).
__device__ __forceinline__ void gl16(const float* g, float* l) {
    __builtin_amdgcn_global_load_lds(
        (const __attribute__((address_space(1))) void*)g,
        (__attribute__((address_space(3))) void*)l, 16, 0, 0);
}

__device__ __forceinline__ float dot4(float4 a, float4 b, float c) {
    c = fmaf(a.x, b.x, c);
    c = fmaf(a.y, b.y, c);
    c = fmaf(a.z, b.z, c);
    c = fmaf(a.w, b.w, c);
    return c;
}

__device__ __forceinline__ float gelu_exact(float g) {
    return 0.5f * g * (1.0f + erff(g * 0.70710678118654752f));
}

// ---------------------------------------------------------------------------
// Kernel 1: h = emb[x]; LN1 stats (mu, rstd). One wave per token.
// ---------------------------------------------------------------------------
__global__ __launch_bounds__(256) void k_embed(const int* __restrict__ x,
                                               const float* __restrict__ emb,
                                               float* __restrict__ h,
                                               float* __restrict__ stats)
{
    int lane = threadIdx.x & 63;
    int wv   = threadIdx.x >> 6;
    int tok  = blockIdx.x * 4 + wv;
    int xi   = x[tok];
    float2 v = ((const float2*)(emb + xi * D))[lane];
    ((float2*)(h + (size_t)tok * D))[lane] = v;
    float s1 = wsum64(v.x + v.y);
    float s2 = wsum64(v.x * v.x + v.y * v.y);
    float mu  = s1 * (1.0f / D);
    float var = s2 * (1.0f / D) - mu * mu;
    if (lane == 0) {
        stats[tok * 2]     = mu;
        stats[tok * 2 + 1] = rsqrtf(var + EPS);
    }
}

// ---------------------------------------------------------------------------
// Kernel 1.5: gx = LN1(h) @ Wg + bias as a tiled GEMM.
// 32 tokens/block, 256 threads; whole Wg (64 KiB) staged once in LDS.
// ---------------------------------------------------------------------------
__global__ __launch_bounds__(256, 2) void k_gx(const float* __restrict__ Wg,    // (4,NH,DH,DH)
                                               const float* __restrict__ bias,  // (NH,4,DH)
                                               const float* __restrict__ lnw,   // (D)
                                               const float* __restrict__ h,     // (B*S, D)
                                               const float* __restrict__ stats, // (B*S, 2)
                                               float* __restrict__ gx)          // (B*NH*S, 128)
{
    __shared__ float xs[32 * 128];        // 16 KiB
    __shared__ float wl[4 * 32 * 128];    // 64 KiB  [n][k][gk'] swizzled

    int tid  = threadIdx.x;
    int lane = tid & 63;
    int wv   = tid >> 6;
    size_t tok0 = (size_t)blockIdx.x * 32;

    // ---- stage all Wg: wl[n][i][g*32+hh ^ sw] = Wg[g][n][hh][i] ----
    {
        int q = tid & 7;                   // float4 index along i
        #pragma unroll
        for (int it = 0; it < 16; ++it) {
            int row = it * 32 + (tid >> 3);        // 0..511 = (g*4+n)*32+hh
            int g  = row >> 7;
            int n  = (row >> 5) & 3;
            int hh = row & 31;
            float4 v = *(const float4*)(Wg + row * 32 + q * 4);
            int col = g * 32 + hh;
            int sw  = q << 2;
            float* dst = wl + n * 4096;
            dst[(q * 4 + 0) * 128 + (col ^ sw)] = v.x;
            dst[(q * 4 + 1) * 128 + (col ^ sw)] = v.y;
            dst[(q * 4 + 2) * 128 + (col ^ sw)] = v.z;
            dst[(q * 4 + 3) * 128 + (col ^ sw)] = v.w;
        }
    }
    // ---- stage xn (LN1 applied; stats precomputed) ----
    for (int i = 0; i < 8; ++i) {
        int t = wv * 8 + i;
        const float* hp = h + (tok0 + t) * D;
        float mu = stats[(tok0 + t) * 2];
        float rs = stats[(tok0 + t) * 2 + 1];
        float v1 = (hp[lane]      - mu) * rs * lnw[lane];
        float v2 = (hp[64 + lane] - mu) * rs * lnw[64 + lane];
        xs[t * 128 + xg(lane)]      = v1;
        xs[t * 128 + xg(lane + 64)] = v2;
    }
    __syncthreads();

    int nh   = lane >> 4;          // head
    int col0 = (lane & 15) * 8;    // 8 output cols within head
    int t0   = wv * 8;             // 8 tokens

    float acc[8][8];
    #pragma unroll
    for (int j = 0; j < 8; ++j)
        #pragma unroll
        for (int cc = 0; cc < 8; ++cc) acc[j][cc] = 0.f;

    const float* wbase = wl + nh * 4096;
    #pragma unroll 4
    for (int k = 0; k < 32; ++k) {
        int sw = (k >> 2) << 2;
        float4 w0 = *(const float4*)&wbase[k * 128 + (col0 ^ sw)];
        float4 w1 = *(const float4*)&wbase[k * 128 + ((col0 + 4) ^ sw)];
        int ac = (nh * 32 + k) ^ (nh << 3);
        #pragma unroll
        for (int j = 0; j < 8; ++j) {
            float a = xs[(t0 + j) * 128 + ac];
            acc[j][0] = fmaf(a, w0.x, acc[j][0]);
            acc[j][1] = fmaf(a, w0.y, acc[j][1]);
            acc[j][2] = fmaf(a, w0.z, acc[j][2]);
            acc[j][3] = fmaf(a, w0.w, acc[j][3]);
            acc[j][4] = fmaf(a, w1.x, acc[j][4]);
            acc[j][5] = fmaf(a, w1.y, acc[j][5]);
            acc[j][6] = fmaf(a, w1.z, acc[j][6]);
            acc[j][7] = fmaf(a, w1.w, acc[j][7]);
        }
    }

    float4 bb0 = *(const float4*)(bias + nh * 128 + col0);
    float4 bb1 = *(const float4*)(bias + nh * 128 + col0 + 4);
    #pragma unroll
    for (int j = 0; j < 8; ++j) {
        int gt = (int)tok0 + t0 + j;
        int bb = gt >> 6;
        int ss = gt & 63;
        float* op = gx + ((size_t)(bb * NH + nh) * S_LEN + ss) * 128 + col0;
        float4 o0v, o1v;
        o0v.x = acc[j][0] + bb0.x; o0v.y = acc[j][1] + bb0.y;
        o0v.z = acc[j][2] + bb0.z; o0v.w = acc[j][3] + bb0.w;
        o1v.x = acc[j][4] + bb1.x; o1v.y = acc[j][5] + bb1.y;
        o1v.z = acc[j][6] + bb1.z; o1v.w = acc[j][7] + bb1.w;
        *(float4*)op       = o0v;
        *(float4*)(op + 4) = o1v;
    }
}

// ---------------------------------------------------------------------------
// Kernel 2: sLSTM scan. R in LDS ([chunk][lane][4], conflict-free); gx/h
// loads 4-deep software-pipelined.
// ---------------------------------------------------------------------------
__global__ __launch_bounds__(64, 1) void k_scan(const float* __restrict__ Rm,   // (NH,DH,4*DH)
                                                const float* __restrict__ gnw,  // (D)
                                                const float* __restrict__ gx,   // (B*NH*S, 128)
                                                float* __restrict__ h)          // (B*S, D) in/out
{
    __shared__ float WA[8][64][4];   // 8 KiB: RA chunks, lane-contiguous
    __shared__ float WB[8][64][4];   // 8 KiB: RB chunks

    int b    = blockIdx.x >> 2;
    int n    = blockIdx.x & 3;
    int lane = threadIdx.x;
    int e    = lane >> 1;
    int sub  = lane & 1;
    int colA = sub * DH + e;           // i (sub0) / f (sub1); +64 -> z/o

    // ---- stage R into LDS (once) ----
    #pragma unroll
    for (int cc = 0; cc < 8; ++cc) {
        float4 a, bv;
        #pragma unroll
        for (int j = 0; j < 4; ++j) {
            ((float*)&a)[j]  = Rm[(n * DH + cc * 4 + j) * 128 + colA];
            ((float*)&bv)[j] = Rm[(n * DH + cc * 4 + j) * 128 + 64 + colA];
        }
        *(float4*)WA[cc][lane] = a;
        *(float4*)WB[cc][lane] = bv;
    }
    float gw = gnw[n * DH + e];
    __syncthreads();

    float c = 0.f, nacc = 0.f, m = 0.f;
    float hu[DH];
    #pragma unroll
    for (int i = 0; i < DH; ++i) hu[i] = 0.f;

    float* hb = h + ((size_t)b * S_LEN) * D + n * DH;
    const float* gxp = gx + ((size_t)(b * NH + n) * S_LEN) * 128;

    // ---- 4-deep software pipeline on gx + residual-h loads ----
    float pGA[4], pGB[4], pHR[4];
    #pragma unroll
    for (int k = 0; k < 4; ++k) {
        pGA[k] = gxp[k * 128 + colA];
        pGB[k] = gxp[k * 128 + 64 + colA];
        pHR[k] = hb[k * D + e];
    }

    #pragma unroll 4
    for (int s = 0; s < S_LEN; ++s) {
        int sp = (s + 4 < S_LEN) ? s + 4 : S_LEN - 1;
        float nGA = gxp[sp * 128 + colA];
        float nGB = gxp[sp * 128 + 64 + colA];
        float nHR = hb[sp * D + e];

        float r0=0,r1=0,r2=0,r3=0,q0=0,q1=0,q2=0,q3=0;
        #pragma unroll
        for (int cc = 0; cc < 8; ++cc) {
            float4 wa = *(const float4*)WA[cc][lane];
            float4 wb = *(const float4*)WB[cc][lane];
            r0 = fmaf(hu[cc*4+0], wa.x, r0);
            r1 = fmaf(hu[cc*4+1], wa.y, r1);
            r2 = fmaf(hu[cc*4+2], wa.z, r2);
            r3 = fmaf(hu[cc*4+3], wa.w, r3);
            q0 = fmaf(hu[cc*4+0], wb.x, q0);
            q1 = fmaf(hu[cc*4+1], wb.y, q1);
            q2 = fmaf(hu[cc*4+2], wb.z, q2);
            q3 = fmaf(hu[cc*4+3], wb.w, q3);
        }
        float rawA = pGA[0] + ((r0 + r1) + (r2 + r3));
        float rawB = pGB[0] + ((q0 + q1) + (q2 + q3));

        float xA = dppf<0xB1>(rawA);   // quad_perm [1,0,3,2] = xor1
        float xB = dppf<0xB1>(rawB);
        float i_r = sub ? xA   : rawA;
        float f_r = sub ? rawA : xA;
        float z_r = sub ? xB   : rawB;
        float o_r = sub ? rawB : xB;

        // log_sigmoid(f) = min(f,0) - ln(1+exp(-|f|)) via hw exp/log2
        float lsf  = fminf(f_r, 0.f)
                   - 0.69314718055994531f * __log2f(1.0f + __expf(-fabsf(f_r)));
        float lfm  = m + lsf;
        float mnew = fmaxf(i_r, lfm);
        float ig   = __expf(i_r - mnew);
        float fg   = __expf(lfm - mnew);
        float t    = __expf(2.f * z_r);
        float tz   = 1.f - 2.f / (t + 1.f);   // tanh, stable both ends
        c    = fg * c + ig * tz;
        nacc = fg * nacc + ig;
        m    = mnew;
        float hv = c / (nacc * (1.f + __expf(-o_r)));   // sigmoid(o)*c/n

        // groupnorm over DH (each element appears twice -> /64)
        float s1 = wsum64(hv);
        float s2 = wsum64(hv * hv);
        float mu  = s1 * (1.f / 64.f);
        float var = s2 * (1.f / 64.f) - mu * mu;
        float hn  = (hv - mu) * rsqrtf(var + EPS) * gw;

        if (!sub) hb[s * D + e] = pHR[0] + hn;   // residual write (h_mid)

        #pragma unroll
        for (int i = 0; i < DH; ++i)
            hu[i] = __int_as_float(
                __builtin_amdgcn_readlane(__float_as_int(hv), 2 * i));

        pGA[0]=pGA[1]; pGA[1]=pGA[2]; pGA[2]=pGA[3]; pGA[3]=nGA;
        pGB[0]=pGB[1]; pGB[1]=pGB[2]; pGB[2]=pGB[3]; pGB[3]=nGB;
        pHR[0]=pHR[1]; pHR[1]=pHR[2]; pHR[2]=pHR[3]; pHR[3]=nHR;
    }
}

// ---------------------------------------------------------------------------
// Kernel 3 (rewritten): fused LN2 -> up GEMM -> GeLU -> down GEMM -> residual
// -> tail. R0 theory: old version was LDS-read-BW bound (2.5 B/FMA, 4.0 GB
// of ds_read = 77 us model vs 72 us measured). New structure:
//   * 64 tokens/block, 512 blocks (= exactly 2 blocks/CU), 256 threads.
//   * thread tile 4 tok x 16 weight rows, k-major dot-product FMAs
//     -> 1.25 B/FMA (UP) / 1.5 (DOWN), ~2.3 GB total -> ~44 us LDS floor.
//   * weights stay in natural [row][k] layout -> staged straight from
//     global with global_load_lds width=16 (no reg round-trip, no ds_write).
//   * k-slot XOR swizzle by (row>>2)&7 applied on the per-lane GLOBAL source
//     address (LDS dest linear, as gload_lds requires) and on the read side;
//     all ds_read patterns <=2-way (free).
//   * act buffer aliases xs (dead after UP) -> LDS = 32+32 KiB, 2 blocks/CU.
// ---------------------------------------------------------------------------
template <int LAST>
__global__ __launch_bounds__(256) void k_ff(float* __restrict__ h,
                                            const float* __restrict__ ln2w,
                                            const float* __restrict__ wup,    // (2D, D)
                                            const float* __restrict__ wdn,    // (D, D)
                                            float* __restrict__ stats_out,
                                            const float* __restrict__ lastw,
                                            const float* __restrict__ projw,
                                            const float* __restrict__ projb,
                                            float* __restrict__ out)
{
    __shared__ float xs[64 * 128];   // 32 KiB: LN2(x) -> act -> hnew (aliased)
    __shared__ float wt[128 * 64];   // 32 KiB: weight chunk

    int tid  = threadIdx.x;
    int lane = tid & 63;
    int wv   = tid >> 6;
    int oi   = lane & 15;            // output-column group (16 per wave)
    int ti   = lane >> 4;            // 0..3
    int tg   = wv * 4 + ti;          // token group 0..15
    int t0   = tg * 4;               // this thread's 4 tokens
    int swv  = oi & 7;               // weight-row k-slot swizzle key
    int swt  = tg & 7;               // activation k-slot swizzle key
    size_t tok0 = (size_t)blockIdx.x * 64;

    // ---- phase 1: LN2 -> xs, slot-swizzled by (t>>2)&7 ----
    for (int i = 0; i < 16; ++i) {
        int t = wv * 16 + i;
        const float* hp = h + (tok0 + t) * D;
        float v1 = hp[lane], v2 = hp[64 + lane];
        float s1 = wsum64(v1 + v2);
        float s2 = wsum64(v1 * v1 + v2 * v2);
        float mu = s1 * (1.0f / D);
        float rs = rsqrtf(s2 * (1.0f / D) - mu * mu + EPS);
        int sx = ((t >> 2) & 7) << 2;
        xs[t * 128 + (lane ^ sx)]        = (v1 - mu) * rs * ln2w[lane];
        xs[t * 128 + ((lane + 64) ^ sx)] = (v2 - mu) * rs * ln2w[64 + lane];
    }

    // ---- UP GEMM: acc[4 tok][gate lo/hi 4+4][val lo/hi 4+4] ----
    float ag0[4][4], ag1[4][4], av0[4][4], av1[4][4];
    #pragma unroll
    for (int a = 0; a < 4; ++a)
        #pragma unroll
        for (int j = 0; j < 4; ++j) { ag0[a][j]=0.f; ag1[a][j]=0.f; av0[a][j]=0.f; av1[a][j]=0.f; }

    for (int c4 = 0; c4 < 4; ++c4) {
        int kc = c4 * 32;
        __syncthreads();   // previous chunk's wt reads done (c4=0: xs writes visible)
        // stage: LDS row r (0..127) = [gate row r | val row r+128], k in [kc,kc+32)
        // slot s&7 holds k-f4 (s&7)^((r>>2)&7); wave-uniform dest + lane*16.
        #pragma unroll
        for (int q = 0; q < 8; ++q) {
            int r  = (q * 4 + wv) * 4 + (lane >> 4);
            int s  = lane & 15;
            int o  = r + ((s >> 3) << 7);
            int sl = (s & 7) ^ ((r >> 2) & 7);
            gl16(wup + o * 128 + kc + (sl << 2), wt + (q * 4 + wv) * 256);
        }
        __syncthreads();   // vmcnt drained per-wave + barrier -> wt ready

        #pragma unroll 2
        for (int k4 = 0; k4 < 8; ++k4) {
            int ac = (((c4 * 8 + k4) ^ swt) << 2);
            float4 a0 = *(const float4*)&xs[(t0 + 0) * 128 + ac];
            float4 a1 = *(const float4*)&xs[(t0 + 1) * 128 + ac];
            float4 a2 = *(const float4*)&xs[(t0 + 2) * 128 + ac];
            float4 a3 = *(const float4*)&xs[(t0 + 3) * 128 + ac];
            int ks = (k4 ^ swv) << 2;
            #pragma unroll
            for (int j = 0; j < 4; ++j) {
                const float* wrl = wt + (oi * 4 + j) * 64;        // rows oi*4+j
                const float* wrh = wrl + 64 * 64;                 // rows 64+oi*4+j
                float4 bgl = *(const float4*)&wrl[ks];
                float4 bvl = *(const float4*)&wrl[32 + ks];
                float4 bgh = *(const float4*)&wrh[ks];
                float4 bvh = *(const float4*)&wrh[32 + ks];
                ag0[0][j] = dot4(a0, bgl, ag0[0][j]);
                ag0[1][j] = dot4(a1, bgl, ag0[1][j]);
                ag0[2][j] = dot4(a2, bgl, ag0[2][j]);
                ag0[3][j] = dot4(a3, bgl, ag0[3][j]);
                av0[0][j] = dot4(a0, bvl, av0[0][j]);
                av0[1][j] = dot4(a1, bvl, av0[1][j]);
                av0[2][j] = dot4(a2, bvl, av0[2][j]);
                av0[3][j] = dot4(a3, bvl, av0[3][j]);
                ag1[0][j] = dot4(a0, bgh, ag1[0][j]);
                ag1[1][j] = dot4(a1, bgh, ag1[1][j]);
                ag1[2][j] = dot4(a2, bgh, ag1[2][j]);
                ag1[3][j] = dot4(a3, bgh, ag1[3][j]);
                av1[0][j] = dot4(a0, bvh, av1[0][j]);
                av1[1][j] = dot4(a1, bvh, av1[1][j]);
                av1[2][j] = dot4(a2, bvh, av1[2][j]);
                av1[3][j] = dot4(a3, bvh, av1[3][j]);
            }
        }
    }

    __syncthreads();   // all UP xs/wt reads complete -> xs reusable as act

    // ---- act = gelu(gate) * val -> xs (same swizzle as LN2 layout) ----
    #pragma unroll
    for (int tt = 0; tt < 4; ++tt) {
        int t = t0 + tt;
        float4 lo, hi;
        lo.x = gelu_exact(ag0[tt][0]) * av0[tt][0];
        lo.y = gelu_exact(ag0[tt][1]) * av0[tt][1];
        lo.z = gelu_exact(ag0[tt][2]) * av0[tt][2];
        lo.w = gelu_exact(ag0[tt][3]) * av0[tt][3];
        hi.x = gelu_exact(ag1[tt][0]) * av1[tt][0];
        hi.y = gelu_exact(ag1[tt][1]) * av1[tt][1];
        hi.z = gelu_exact(ag1[tt][2]) * av1[tt][2];
        hi.w = gelu_exact(ag1[tt][3]) * av1[tt][3];
        int sb = (oi ^ swt) << 2;
        *(float4*)&xs[t * 128 + sb]      = lo;
        *(float4*)&xs[t * 128 + 64 + sb] = hi;
    }

    // ---- DOWN GEMM ----
    float ad0[4][4], ad1[4][4];
    #pragma unroll
    for (int a = 0; a < 4; ++a)
        #pragma unroll
        for (int j = 0; j < 4; ++j) { ad0[a][j]=0.f; ad1[a][j]=0.f; }

    for (int ch = 0; ch < 2; ++ch) {
        int cc = ch * 64;
        // stage wdn rows 0..127, cols [cc,cc+64); 16 f4-slots/row, same swizzle
        #pragma unroll
        for (int q = 0; q < 8; ++q) {
            int r  = (q * 4 + wv) * 4 + (lane >> 4);
            int s  = lane & 15;
            int sl = s ^ ((r >> 2) & 7);
            gl16(wdn + r * 128 + cc + (sl << 2), wt + (q * 4 + wv) * 256);
        }
        __syncthreads();   // wt ready AND act writes visible (first iter)

        #pragma unroll 4
        for (int u4 = 0; u4 < 16; ++u4) {
            int ac = (((ch * 16 + u4) ^ swt) << 2);
            float4 a0 = *(const float4*)&xs[(t0 + 0) * 128 + ac];
            float4 a1 = *(const float4*)&xs[(t0 + 1) * 128 + ac];
            float4 a2 = *(const float4*)&xs[(t0 + 2) * 128 + ac];
            float4 a3 = *(const float4*)&xs[(t0 + 3) * 128 + ac];
            int ks = (u4 ^ swv) << 2;
            #pragma unroll
            for (int j = 0; j < 4; ++j) {
                const float* wrl = wt + (oi * 4 + j) * 64;
                const float* wrh = wrl + 64 * 64;
                float4 b0 = *(const float4*)&wrl[ks];
                float4 b1 = *(const float4*)&wrh[ks];
                ad0[0][j] = dot4(a0, b0, ad0[0][j]);
                ad0[1][j] = dot4(a1, b0, ad0[1][j]);
                ad0[2][j] = dot4(a2, b0, ad0[2][j]);
                ad0[3][j] = dot4(a3, b0, ad0[3][j]);
                ad1[0][j] = dot4(a0, b1, ad1[0][j]);
                ad1[1][j] = dot4(a1, b1, ad1[1][j]);
                ad1[2][j] = dot4(a2, b1, ad1[2][j]);
                ad1[3][j] = dot4(a3, b1, ad1[3][j]);
            }
        }
        __syncthreads();   // wt/xs reads done before next stage / epilogue stash
    }

    // ---- epilogue: residual add, stash hnew in xs ----
    #pragma unroll
    for (int tt = 0; tt < 4; ++tt) {
        int t = t0 + tt;
        size_t tok = tok0 + t;
        float4 r0v = *(const float4*)(h + tok * D + oi * 4);
        float4 r1v = *(const float4*)(h + tok * D + 64 + oi * 4);
        float4 h0, h1;
        h0.x = r0v.x + ad0[tt][0]; h0.y = r0v.y + ad0[tt][1];
        h0.z = r0v.z + ad0[tt][2]; h0.w = r0v.w + ad0[tt][3];
        h1.x = r1v.x + ad1[tt][0]; h1.y = r1v.y + ad1[tt][1];
        h1.z = r1v.z + ad1[tt][2]; h1.w = r1v.w + ad1[tt][3];
        if (!LAST) {
            *(float4*)(h + tok * D + oi * 4)      = h0;
            *(float4*)(h + tok * D + 64 + oi * 4) = h1;
        }
        int sb = (oi ^ swt) << 2;
        *(float4*)&xs[t * 128 + sb]      = h0;
        *(float4*)&xs[t * 128 + 64 + sb] = h1;
    }
    __syncthreads();

    // ---- final per-token phase ----
    if (!LAST) {
        for (int i = 0; i < 16; ++i) {
            int t = wv * 16 + i;
            int sx = ((t >> 2) & 7) << 2;
            float v1 = xs[t * 128 + (lane ^ sx)];
            float v2 = xs[t * 128 + ((lane + 64) ^ sx)];
            float s1 = wsum64(v1 + v2);
            float s2 = wsum64(v1 * v1 + v2 * v2);
            float mu = s1 * (1.0f / D);
            float rs = rsqrtf(s2 * (1.0f / D) - mu * mu + EPS);
            if (lane == 0) {
                stats_out[(tok0 + t) * 2]     = mu;
                stats_out[(tok0 + t) * 2 + 1] = rs;
            }
        }
    } else {
        float pw1[VOCAB], pw2[VOCAB], pb[VOCAB];
        #pragma unroll
        for (int v = 0; v < VOCAB; ++v) {
            pw1[v] = projw[v * D + lane];
            pw2[v] = projw[v * D + 64 + lane];
            pb[v]  = projb[v];
        }
        for (int i = 0; i < 16; ++i) {
            int t = wv * 16 + i;
            int sx = ((t >> 2) & 7) << 2;
            float v1 = xs[t * 128 + (lane ^ sx)];
            float v2 = xs[t * 128 + ((lane + 64) ^ sx)];
            float s1 = wsum64(v1 + v2);
            float s2 = wsum64(v1 * v1 + v2 * v2);
            float mu = s1 * (1.0f / D);
            float rs = rsqrtf(s2 * (1.0f / D) - mu * mu + EPS);
            float x1 = (v1 - mu) * rs * lastw[lane];
            float x2 = (v2 - mu) * rs * lastw[64 + lane];
            #pragma unroll
            for (int v = 0; v < VOCAB; ++v) {
                float pp = wsum64(fmaf(x1, pw1[v], x2 * pw2[v]));
                if (lane == 0) out[(tok0 + t) * VOCAB + v] = pp + pb[v];
            }
        }
    }
}

// ---------------------------------------------------------------------------
extern "C" void kernel_launch(void* const* d_in, const int* in_sizes, int n_in,
                              void* d_out, int out_size, void* d_ws, size_t ws_size,
                              hipStream_t stream)
{
    const int*   x     = (const int*)  d_in[0];
    const float* emb   = (const float*)d_in[1];
    const float* ln1   = (const float*)d_in[2];
    const float* Wg    = (const float*)d_in[3];
    const float* Rm    = (const float*)d_in[4];
    const float* bias  = (const float*)d_in[5];
    const float* gnw   = (const float*)d_in[6];
    const float* ln2   = (const float*)d_in[7];
    const float* wup   = (const float*)d_in[8];
    const float* wdn   = (const float*)d_in[9];
    const float* postw = (const float*)d_in[10];
    const float* projw = (const float*)d_in[11];
    const float* projb = (const float*)d_in[12];
    float* out   = (float*)d_out;
    float* hbuf  = (float*)d_ws;                       // (B*S, D)
    float* stats = hbuf + (size_t)NTOK * D;            // (B*S, 2)
    float* gxbuf = stats + (size_t)NTOK * 2;           // (B*NH*S, 128)

    k_embed<<<NTOK / 4, 256, 0, stream>>>(x, emb, hbuf, stats);

    for (int bi = 0; bi < NB; ++bi) {
        k_gx<<<NTOK / 32, 256, 0, stream>>>(Wg + bi * 4 * NH * DH * DH,
                                            bias + bi * NH * 4 * DH,
                                            ln1 + bi * D,
                                            hbuf, stats, gxbuf);
        k_scan<<<B_SZ * NH, 64, 0, stream>>>(Rm + bi * NH * DH * 4 * DH,
                                             gnw + bi * D,
                                             gxbuf, hbuf);
        if (bi == 0)
            k_ff<0><<<NTOK / 64, 256, 0, stream>>>(hbuf, ln2 + bi * D,
                                                   wup + bi * 2 * D * D,
                                                   wdn + bi * D * D,
                                                   stats, nullptr, nullptr,
                                                   nullptr, nullptr);
        else
            k_ff<1><<<NTOK / 64, 256, 0, stream>>>(hbuf, ln2 + bi * D,
                                                   wup + bi * 2 * D * D,
                                                   wdn + bi * D * D,
                                                   nullptr, postw, projw,
                                                   projb, out);
    }
}

// Round 2
// 389.441 us; speedup vs baseline: 1.0161x; 1.0161x over previous
//
#include <hip/hip_runtime.h>
#include <math.h>

#define D      128
#define S_LEN  64
#define B_SZ   512
#define NH     4
#define DH     32
#define NB     2
#define VOCAB  9
#define EPS    1e-5f
#define NTOK   (B_SZ * S_LEN)

// ---------------- DPP helpers (ctrl must be compile-time constant) ----------
template <int CTRL>
__device__ __forceinline__ float dppf(float x) {
    return __int_as_float(__builtin_amdgcn_update_dpp(
        0, __float_as_int(x), CTRL, 0xF, 0xF, true));
}
// wave64 sum -> wave-uniform scalar (canonical row_shr/bcast sequence)
__device__ __forceinline__ float wsum64(float x) {
    x += dppf<0x111>(x);  // row_shr:1
    x += dppf<0x112>(x);  // row_shr:2
    x += dppf<0x114>(x);  // row_shr:4
    x += dppf<0x118>(x);  // row_shr:8
    x += dppf<0x142>(x);  // row_bcast:15
    x += dppf<0x143>(x);  // row_bcast:31
    return __int_as_float(__builtin_amdgcn_readlane(__float_as_int(x), 63));
}

// LDS swizzles (all xor bits>=2 -> float4 alignment preserved)
__device__ __forceinline__ int xc3(int t, int c) { return c ^ (((t >> 1) & 7) << 2); }
// act-buffer swizzle: key spreads both ti (t>>2) and tt (t&3) across the 8
// bank-groups; with 4-token tiles the old (t&7) key collapses to 2 values
// per wave (4ti&7 in {0,4}) -> cross-quarter same-bank rows (the R1 conflict
// signature). (5*(t>>2)+(t&3))&7 gives 4 distinct keys per wave per instr.
__device__ __forceinline__ int xa2(int t, int c) {
    return c ^ (((((t >> 2) * 5) + (t & 3)) & 7) << 2);
}
__device__ __forceinline__ int xg (int c)        { return c ^ ((c >> 5) << 3); }

__device__ __forceinline__ float gelu_exact(float g) {
    return 0.5f * g * (1.0f + erff(g * 0.70710678118654752f));
}

// ---------------------------------------------------------------------------
// Kernel 1: h = emb[x]; LN1 stats (mu, rstd). One wave per token.
// ---------------------------------------------------------------------------
__global__ __launch_bounds__(256) void k_embed(const int* __restrict__ x,
                                               const float* __restrict__ emb,
                                               float* __restrict__ h,
                                               float* __restrict__ stats)
{
    int lane = threadIdx.x & 63;
    int wv   = threadIdx.x >> 6;
    int tok  = blockIdx.x * 4 + wv;
    int xi   = x[tok];
    float2 v = ((const float2*)(emb + xi * D))[lane];
    ((float2*)(h + (size_t)tok * D))[lane] = v;
    float s1 = wsum64(v.x + v.y);
    float s2 = wsum64(v.x * v.x + v.y * v.y);
    float mu  = s1 * (1.0f / D);
    float var = s2 * (1.0f / D) - mu * mu;
    if (lane == 0) {
        stats[tok * 2]     = mu;
        stats[tok * 2 + 1] = rsqrtf(var + EPS);
    }
}

// ---------------------------------------------------------------------------
// Kernel 1.5: gx = LN1(h) @ Wg + bias as a tiled GEMM.
// 32 tokens/block, 256 threads; whole Wg (64 KiB) staged once in LDS.
// ---------------------------------------------------------------------------
__global__ __launch_bounds__(256, 2) void k_gx(const float* __restrict__ Wg,    // (4,NH,DH,DH)
                                               const float* __restrict__ bias,  // (NH,4,DH)
                                               const float* __restrict__ lnw,   // (D)
                                               const float* __restrict__ h,     // (B*S, D)
                                               const float* __restrict__ stats, // (B*S, 2)
                                               float* __restrict__ gx)          // (B*NH*S, 128)
{
    __shared__ float xs[32 * 128];        // 16 KiB
    __shared__ float wl[4 * 32 * 128];    // 64 KiB  [n][k][gk'] swizzled

    int tid  = threadIdx.x;
    int lane = tid & 63;
    int wv   = tid >> 6;
    size_t tok0 = (size_t)blockIdx.x * 32;

    // ---- stage all Wg: wl[n][i][g*32+hh ^ sw] = Wg[g][n][hh][i] ----
    {
        int q = tid & 7;                   // float4 index along i
        #pragma unroll
        for (int it = 0; it < 16; ++it) {
            int row = it * 32 + (tid >> 3);        // 0..511 = (g*4+n)*32+hh
            int g  = row >> 7;
            int n  = (row >> 5) & 3;
            int hh = row & 31;
            float4 v = *(const float4*)(Wg + row * 32 + q * 4);
            int col = g * 32 + hh;
            int sw  = q << 2;
            float* dst = wl + n * 4096;
            dst[(q * 4 + 0) * 128 + (col ^ sw)] = v.x;
            dst[(q * 4 + 1) * 128 + (col ^ sw)] = v.y;
            dst[(q * 4 + 2) * 128 + (col ^ sw)] = v.z;
            dst[(q * 4 + 3) * 128 + (col ^ sw)] = v.w;
        }
    }
    // ---- stage xn (LN1 applied; stats precomputed) ----
    for (int i = 0; i < 8; ++i) {
        int t = wv * 8 + i;
        const float* hp = h + (tok0 + t) * D;
        float mu = stats[(tok0 + t) * 2];
        float rs = stats[(tok0 + t) * 2 + 1];
        float v1 = (hp[lane]      - mu) * rs * lnw[lane];
        float v2 = (hp[64 + lane] - mu) * rs * lnw[64 + lane];
        xs[t * 128 + xg(lane)]      = v1;
        xs[t * 128 + xg(lane + 64)] = v2;
    }
    __syncthreads();

    int nh   = lane >> 4;          // head
    int col0 = (lane & 15) * 8;    // 8 output cols within head
    int t0   = wv * 8;             // 8 tokens

    float acc[8][8];
    #pragma unroll
    for (int j = 0; j < 8; ++j)
        #pragma unroll
        for (int cc = 0; cc < 8; ++cc) acc[j][cc] = 0.f;

    const float* wbase = wl + nh * 4096;
    #pragma unroll 4
    for (int k = 0; k < 32; ++k) {
        int sw = (k >> 2) << 2;
        float4 w0 = *(const float4*)&wbase[k * 128 + (col0 ^ sw)];
        float4 w1 = *(const float4*)&wbase[k * 128 + ((col0 + 4) ^ sw)];
        int ac = (nh * 32 + k) ^ (nh << 3);
        #pragma unroll
        for (int j = 0; j < 8; ++j) {
            float a = xs[(t0 + j) * 128 + ac];
            acc[j][0] = fmaf(a, w0.x, acc[j][0]);
            acc[j][1] = fmaf(a, w0.y, acc[j][1]);
            acc[j][2] = fmaf(a, w0.z, acc[j][2]);
            acc[j][3] = fmaf(a, w0.w, acc[j][3]);
            acc[j][4] = fmaf(a, w1.x, acc[j][4]);
            acc[j][5] = fmaf(a, w1.y, acc[j][5]);
            acc[j][6] = fmaf(a, w1.z, acc[j][6]);
            acc[j][7] = fmaf(a, w1.w, acc[j][7]);
        }
    }

    float4 bb0 = *(const float4*)(bias + nh * 128 + col0);
    float4 bb1 = *(const float4*)(bias + nh * 128 + col0 + 4);
    #pragma unroll
    for (int j = 0; j < 8; ++j) {
        int gt = (int)tok0 + t0 + j;
        int bb = gt >> 6;
        int ss = gt & 63;
        float* op = gx + ((size_t)(bb * NH + nh) * S_LEN + ss) * 128 + col0;
        float4 o0v, o1v;
        o0v.x = acc[j][0] + bb0.x; o0v.y = acc[j][1] + bb0.y;
        o0v.z = acc[j][2] + bb0.z; o0v.w = acc[j][3] + bb0.w;
        o1v.x = acc[j][4] + bb1.x; o1v.y = acc[j][5] + bb1.y;
        o1v.z = acc[j][6] + bb1.z; o1v.w = acc[j][7] + bb1.w;
        *(float4*)op       = o0v;
        *(float4*)(op + 4) = o1v;
    }
}

// ---------------------------------------------------------------------------
// Kernel 2: sLSTM scan. R in LDS ([chunk][lane][4], conflict-free); gx/h
// loads 4-deep software-pipelined.
// ---------------------------------------------------------------------------
__global__ __launch_bounds__(64, 1) void k_scan(const float* __restrict__ Rm,   // (NH,DH,4*DH)
                                                const float* __restrict__ gnw,  // (D)
                                                const float* __restrict__ gx,   // (B*NH*S, 128)
                                                float* __restrict__ h)          // (B*S, D) in/out
{
    __shared__ float WA[8][64][4];   // 8 KiB: RA chunks, lane-contiguous
    __shared__ float WB[8][64][4];   // 8 KiB: RB chunks

    int b    = blockIdx.x >> 2;
    int n    = blockIdx.x & 3;
    int lane = threadIdx.x;
    int e    = lane >> 1;
    int sub  = lane & 1;
    int colA = sub * DH + e;           // i (sub0) / f (sub1); +64 -> z/o

    // ---- stage R into LDS (once) ----
    #pragma unroll
    for (int cc = 0; cc < 8; ++cc) {
        float4 a, bv;
        #pragma unroll
        for (int j = 0; j < 4; ++j) {
            ((float*)&a)[j]  = Rm[(n * DH + cc * 4 + j) * 128 + colA];
            ((float*)&bv)[j] = Rm[(n * DH + cc * 4 + j) * 128 + 64 + colA];
        }
        *(float4*)WA[cc][lane] = a;
        *(float4*)WB[cc][lane] = bv;
    }
    float gw = gnw[n * DH + e];
    __syncthreads();

    float c = 0.f, nacc = 0.f, m = 0.f;
    float hu[DH];
    #pragma unroll
    for (int i = 0; i < DH; ++i) hu[i] = 0.f;

    float* hb = h + ((size_t)b * S_LEN) * D + n * DH;
    const float* gxp = gx + ((size_t)(b * NH + n) * S_LEN) * 128;

    // ---- 4-deep software pipeline on gx + residual-h loads ----
    float pGA[4], pGB[4], pHR[4];
    #pragma unroll
    for (int k = 0; k < 4; ++k) {
        pGA[k] = gxp[k * 128 + colA];
        pGB[k] = gxp[k * 128 + 64 + colA];
        pHR[k] = hb[k * D + e];
    }

    #pragma unroll 4
    for (int s = 0; s < S_LEN; ++s) {
        int sp = (s + 4 < S_LEN) ? s + 4 : S_LEN - 1;
        float nGA = gxp[sp * 128 + colA];
        float nGB = gxp[sp * 128 + 64 + colA];
        float nHR = hb[sp * D + e];

        float r0=0,r1=0,r2=0,r3=0,q0=0,q1=0,q2=0,q3=0;
        #pragma unroll
        for (int cc = 0; cc < 8; ++cc) {
            float4 wa = *(const float4*)WA[cc][lane];
            float4 wb = *(const float4*)WB[cc][lane];
            r0 = fmaf(hu[cc*4+0], wa.x, r0);
            r1 = fmaf(hu[cc*4+1], wa.y, r1);
            r2 = fmaf(hu[cc*4+2], wa.z, r2);
            r3 = fmaf(hu[cc*4+3], wa.w, r3);
            q0 = fmaf(hu[cc*4+0], wb.x, q0);
            q1 = fmaf(hu[cc*4+1], wb.y, q1);
            q2 = fmaf(hu[cc*4+2], wb.z, q2);
            q3 = fmaf(hu[cc*4+3], wb.w, q3);
        }
        float rawA = pGA[0] + ((r0 + r1) + (r2 + r3));
        float rawB = pGB[0] + ((q0 + q1) + (q2 + q3));

        float xA = dppf<0xB1>(rawA);   // quad_perm [1,0,3,2] = xor1
        float xB = dppf<0xB1>(rawB);
        float i_r = sub ? xA   : rawA;
        float f_r = sub ? rawA : xA;
        float z_r = sub ? xB   : rawB;
        float o_r = sub ? rawB : xB;

        // log_sigmoid(f) = min(f,0) - ln(1+exp(-|f|)) via hw exp/log2
        float lsf  = fminf(f_r, 0.f)
                   - 0.69314718055994531f * __log2f(1.0f + __expf(-fabsf(f_r)));
        float lfm  = m + lsf;
        float mnew = fmaxf(i_r, lfm);
        float ig   = __expf(i_r - mnew);
        float fg   = __expf(lfm - mnew);
        float t    = __expf(2.f * z_r);
        float tz   = 1.f - 2.f / (t + 1.f);   // tanh, stable both ends
        c    = fg * c + ig * tz;
        nacc = fg * nacc + ig;
        m    = mnew;
        float hv = c / (nacc * (1.f + __expf(-o_r)));   // sigmoid(o)*c/n

        // groupnorm over DH (each element appears twice -> /64)
        float s1 = wsum64(hv);
        float s2 = wsum64(hv * hv);
        float mu  = s1 * (1.f / 64.f);
        float var = s2 * (1.f / 64.f) - mu * mu;
        float hn  = (hv - mu) * rsqrtf(var + EPS) * gw;

        if (!sub) hb[s * D + e] = pHR[0] + hn;   // residual write (h_mid)

        #pragma unroll
        for (int i = 0; i < DH; ++i)
            hu[i] = __int_as_float(
                __builtin_amdgcn_readlane(__float_as_int(hv), 2 * i));

        pGA[0]=pGA[1]; pGA[1]=pGA[2]; pGA[2]=pGA[3]; pGA[3]=nGA;
        pGB[0]=pGB[1]; pGB[1]=pGB[2]; pGB[2]=pGB[3]; pGB[3]=nGB;
        pHR[0]=pHR[1]; pHR[1]=pHR[2]; pHR[2]=pHR[3]; pHR[3]=nHR;
    }
}

// ---------------------------------------------------------------------------
// Kernel 3: fused LN2 -> up GEMM -> GeLU -> down GEMM -> residual -> tail.
// R1 post-mortem: [out][k]-rowed LDS weights (stride-256B lane reads) cost
// 4 conflict-cycles per b-read; gl16+drain at 2 blk/CU lost the pipeline.
// This version: R0 structure verbatim (wt [k][out] single-row b-reads = 0
// conflicts; ffld/fst register double-buffer; 40 KiB LDS = 4 blk/CU), with
// the register tile enlarged Tt=2->4 tokens via 128 threads (8 ti x 16 oi):
// per k4 = 4 a-float4 + 8 b-float4 = 192 B / 128 FMAs = 1.5 B/FMA (was 2.5).
// Each thread stages two (q,r0) units (pre[8]). as_ swizzle re-keyed (xa2)
// so 4-token tiles still spread ti across bank-groups.
// ---------------------------------------------------------------------------
template <int LAST>
__global__ __launch_bounds__(128, 2) void k_ff(float* __restrict__ h,
                                               const float* __restrict__ ln2w,
                                               const float* __restrict__ wup,    // (2D, D)
                                               const float* __restrict__ wdn,    // (D, D)
                                               float* __restrict__ stats_out,
                                               const float* __restrict__ lastw,
                                               const float* __restrict__ projw,
                                               const float* __restrict__ projb,
                                               float* __restrict__ out)
{
    __shared__ float xs[32 * 128];      // 16 KiB
    __shared__ float as_[32 * 64];      // 8 KiB
    __shared__ float wt[2 * 32 * 64];   // 16 KiB  [slot][k][o'] swizzled

    int tid  = threadIdx.x;
    int lane = tid & 63;
    int wv   = tid >> 6;               // 0..1
    size_t tok0 = (size_t)blockIdx.x * 32;

    // ---- phase 1: LN2 into xs ----
    for (int i = 0; i < 16; ++i) {
        int t = wv * 16 + i;
        const float* hp = h + (tok0 + t) * D;
        float v1 = hp[lane], v2 = hp[64 + lane];
        float s1 = wsum64(v1 + v2);
        float s2 = wsum64(v1 * v1 + v2 * v2);
        float mu = s1 * (1.0f / D);
        float rs = rsqrtf(s2 * (1.0f / D) - mu * mu + EPS);
        xs[t * D + xc3(t, lane)]      = (v1 - mu) * rs * ln2w[lane];
        xs[t * D + xc3(t, lane + 64)] = (v2 - mu) * rs * ln2w[64 + lane];
    }

    // staging constants: q = float4 idx along k; each thread owns TWO
    // out-row units r0 and r0+16 (128 threads cover the 8q x 32r space).
    int q  = tid & 7;
    int r0 = tid >> 3;          // 0..15
    int kb = q * 4;

    auto ffld = [&](int id, float4* pre) {
        int p = (id >= 6) ? 1 : 0;
        int j = id - p * 6;
        const float* b0;
        const float* b1;
        if (j < 4) { b0 = wup + (p * 64) * D + j * 32;
                     b1 = wup + (128 + p * 64) * D + j * 32; }
        else       { int jj = j - 4;
                     b0 = wdn + p * 64 + jj * 32;
                     b1 = wdn + 64 * D + p * 64 + jj * 32; }
        #pragma unroll
        for (int u = 0; u < 2; ++u) {
            int ru = r0 + u * 16;
            int g0 = ru * D + q * 4;
            int g1 = (ru + 32) * D + q * 4;
            pre[u * 4 + 0] = *(const float4*)(b0 + g0);
            pre[u * 4 + 1] = *(const float4*)(b0 + g1);
            pre[u * 4 + 2] = *(const float4*)(b1 + g0);
            pre[u * 4 + 3] = *(const float4*)(b1 + g1);
        }
    };
    auto fst = [&](const float4* pre) {
        #pragma unroll
        for (int u = 0; u < 2; ++u) {
            int ru = r0 + u * 16;
            int su = ru ^ (q << 2);
            #pragma unroll
            for (int cc = 0; cc < 4; ++cc) {
                const float* p0 = (const float*)&pre[u * 4 + 0];
                const float* p1 = (const float*)&pre[u * 4 + 1];
                const float* p2 = (const float*)&pre[u * 4 + 2];
                const float* p3 = (const float*)&pre[u * 4 + 3];
                wt[(kb + cc) * 64 + su]             = p0[cc];
                wt[(kb + cc) * 64 + su + 32]        = p1[cc];
                wt[2048 + (kb + cc) * 64 + su]      = p2[cc];
                wt[2048 + (kb + cc) * 64 + su + 32] = p3[cc];
            }
        }
    };

    int ti = tid >> 4;    // 0..7
    int oi = tid & 15;    // 0..15
    int t0 = ti * 4;
    int o0 = oi * 4;

    float accd[2][4][4];
    #pragma unroll
    for (int a1 = 0; a1 < 2; ++a1)
        #pragma unroll
        for (int tt = 0; tt < 4; ++tt)
            #pragma unroll
            for (int cc = 0; cc < 4; ++cc) accd[a1][tt][cc] = 0.f;

    float4 pre[8];
    ffld(0, pre);
    int id = 1;

    #pragma unroll
    for (int p = 0; p < 2; ++p) {
        float accg[4][4], accv[4][4];
        #pragma unroll
        for (int tt = 0; tt < 4; ++tt)
            #pragma unroll
            for (int cc = 0; cc < 4; ++cc) { accg[tt][cc] = 0.f; accv[tt][cc] = 0.f; }

        // ---- UP: 4 chunks of 32 k ----
        for (int c4 = 0; c4 < 4; ++c4) {
            __syncthreads();
            fst(pre);
            if (id < 12) ffld(id, pre);
            ++id;
            __syncthreads();
            int kc = c4 * 32;
            #pragma unroll 2
            for (int k4 = 0; k4 < 8; ++k4) {
                float4 a[4];
                #pragma unroll
                for (int tt = 0; tt < 4; ++tt)
                    a[tt] = *(const float4*)&xs[(t0 + tt) * D + xc3(t0 + tt, kc + k4 * 4)];
                int ws = k4 << 2;
                #pragma unroll
                for (int i = 0; i < 4; ++i) {
                    int k = k4 * 4 + i;
                    float4 bg = *(const float4*)&wt[k * 64 + (o0 ^ ws)];
                    float4 bv = *(const float4*)&wt[2048 + k * 64 + (o0 ^ ws)];
                    #pragma unroll
                    for (int tt = 0; tt < 4; ++tt) {
                        float ax = ((const float*)&a[tt])[i];
                        accg[tt][0] = fmaf(ax, bg.x, accg[tt][0]);
                        accg[tt][1] = fmaf(ax, bg.y, accg[tt][1]);
                        accg[tt][2] = fmaf(ax, bg.z, accg[tt][2]);
                        accg[tt][3] = fmaf(ax, bg.w, accg[tt][3]);
                        accv[tt][0] = fmaf(ax, bv.x, accv[tt][0]);
                        accv[tt][1] = fmaf(ax, bv.y, accv[tt][1]);
                        accv[tt][2] = fmaf(ax, bv.z, accv[tt][2]);
                        accv[tt][3] = fmaf(ax, bv.w, accv[tt][3]);
                    }
                }
            }
        }
        // act = gelu_exact(gate) * val -> as_
        #pragma unroll
        for (int tt = 0; tt < 4; ++tt) {
            int t = t0 + tt;
            float4 av;
            float* ap = (float*)&av;
            #pragma unroll
            for (int cc = 0; cc < 4; ++cc)
                ap[cc] = gelu_exact(accg[tt][cc]) * accv[tt][cc];
            *(float4*)&as_[t * 64 + xa2(t, o0)] = av;
        }
        // ---- DOWN: 2 chunks of 32 k ----
        for (int c2 = 0; c2 < 2; ++c2) {
            __syncthreads();
            fst(pre);
            if (id < 12) ffld(id, pre);
            ++id;
            __syncthreads();
            int kc = c2 * 32;
            #pragma unroll 2
            for (int k4 = 0; k4 < 8; ++k4) {
                float4 a[4];
                #pragma unroll
                for (int tt = 0; tt < 4; ++tt)
                    a[tt] = *(const float4*)&as_[(t0 + tt) * 64 + xa2(t0 + tt, kc + k4 * 4)];
                int ws = k4 << 2;
                #pragma unroll
                for (int i = 0; i < 4; ++i) {
                    int k = k4 * 4 + i;
                    float4 b0v = *(const float4*)&wt[k * 64 + (o0 ^ ws)];
                    float4 b1v = *(const float4*)&wt[2048 + k * 64 + (o0 ^ ws)];
                    #pragma unroll
                    for (int tt = 0; tt < 4; ++tt) {
                        float ax = ((const float*)&a[tt])[i];
                        accd[0][tt][0] = fmaf(ax, b0v.x, accd[0][tt][0]);
                        accd[0][tt][1] = fmaf(ax, b0v.y, accd[0][tt][1]);
                        accd[0][tt][2] = fmaf(ax, b0v.z, accd[0][tt][2]);
                        accd[0][tt][3] = fmaf(ax, b0v.w, accd[0][tt][3]);
                        accd[1][tt][0] = fmaf(ax, b1v.x, accd[1][tt][0]);
                        accd[1][tt][1] = fmaf(ax, b1v.y, accd[1][tt][1]);
                        accd[1][tt][2] = fmaf(ax, b1v.z, accd[1][tt][2]);
                        accd[1][tt][3] = fmaf(ax, b1v.w, accd[1][tt][3]);
                    }
                }
            }
        }
    }

    // ---- epilogue: residual add, stash hnew in xs ----
    #pragma unroll
    for (int tt = 0; tt < 4; ++tt) {
        int t = t0 + tt;
        size_t tok = tok0 + t;
        #pragma unroll
        for (int a1 = 0; a1 < 2; ++a1) {
            int cb = a1 * 64 + o0;
            float4 hres = *(const float4*)(h + tok * D + cb);
            float4 hn;
            hn.x = hres.x + accd[a1][tt][0];
            hn.y = hres.y + accd[a1][tt][1];
            hn.z = hres.z + accd[a1][tt][2];
            hn.w = hres.w + accd[a1][tt][3];
            if (!LAST) *(float4*)(h + tok * D + cb) = hn;
            *(float4*)&xs[t * D + xc3(t, cb)] = hn;
        }
    }
    __syncthreads();

    // ---- final per-token phase ----
    if (!LAST) {
        for (int i = 0; i < 16; ++i) {
            int t = wv * 16 + i;
            float v1 = xs[t * D + xc3(t, lane)];
            float v2 = xs[t * D + xc3(t, lane + 64)];
            float s1 = wsum64(v1 + v2);
            float s2 = wsum64(v1 * v1 + v2 * v2);
            float mu = s1 * (1.0f / D);
            float rs = rsqrtf(s2 * (1.0f / D) - mu * mu + EPS);
            if (lane == 0) {
                stats_out[(tok0 + t) * 2]     = mu;
                stats_out[(tok0 + t) * 2 + 1] = rs;
            }
        }
    } else {
        float pw1[VOCAB], pw2[VOCAB], pb[VOCAB];
        #pragma unroll
        for (int v = 0; v < VOCAB; ++v) {
            pw1[v] = projw[v * D + lane];
            pw2[v] = projw[v * D + 64 + lane];
            pb[v]  = projb[v];
        }
        for (int i = 0; i < 16; ++i) {
            int t = wv * 16 + i;
            float v1 = xs[t * D + xc3(t, lane)];
            float v2 = xs[t * D + xc3(t, lane + 64)];
            float s1 = wsum64(v1 + v2);
            float s2 = wsum64(v1 * v1 + v2 * v2);
            float mu = s1 * (1.0f / D);
            float rs = rsqrtf(s2 * (1.0f / D) - mu * mu + EPS);
            float x1 = (v1 - mu) * rs * lastw[lane];
            float x2 = (v2 - mu) * rs * lastw[64 + lane];
            #pragma unroll
            for (int v = 0; v < VOCAB; ++v) {
                float pp = wsum64(fmaf(x1, pw1[v], x2 * pw2[v]));
                if (lane == 0) out[(tok0 + t) * VOCAB + v] = pp + pb[v];
            }
        }
    }
}

// ---------------------------------------------------------------------------
extern "C" void kernel_launch(void* const* d_in, const int* in_sizes, int n_in,
                              void* d_out, int out_size, void* d_ws, size_t ws_size,
                              hipStream_t stream)
{
    const int*   x     = (const int*)  d_in[0];
    const float* emb   = (const float*)d_in[1];
    const float* ln1   = (const float*)d_in[2];
    const float* Wg    = (const float*)d_in[3];
    const float* Rm    = (const float*)d_in[4];
    const float* bias  = (const float*)d_in[5];
    const float* gnw   = (const float*)d_in[6];
    const float* ln2   = (const float*)d_in[7];
    const float* wup   = (const float*)d_in[8];
    const float* wdn   = (const float*)d_in[9];
    const float* postw = (const float*)d_in[10];
    const float* projw = (const float*)d_in[11];
    const float* projb = (const float*)d_in[12];
    float* out   = (float*)d_out;
    float* hbuf  = (float*)d_ws;                       // (B*S, D)
    float* stats = hbuf + (size_t)NTOK * D;            // (B*S, 2)
    float* gxbuf = stats + (size_t)NTOK * 2;           // (B*NH*S, 128)

    k_embed<<<NTOK / 4, 256, 0, stream>>>(x, emb, hbuf, stats);

    for (int bi = 0; bi < NB; ++bi) {
        k_gx<<<NTOK / 32, 256, 0, stream>>>(Wg + bi * 4 * NH * DH * DH,
                                            bias + bi * NH * 4 * DH,
                                            ln1 + bi * D,
                                            hbuf, stats, gxbuf);
        k_scan<<<B_SZ * NH, 64, 0, stream>>>(Rm + bi * NH * DH * 4 * DH,
                                             gnw + bi * D,
                                             gxbuf, hbuf);
        if (bi == 0)
            k_ff<0><<<NTOK / 32, 128, 0, stream>>>(hbuf, ln2 + bi * D,
                                                   wup + bi * 2 * D * D,
                                                   wdn + bi * D * D,
                                                   stats, nullptr, nullptr,
                                                   nullptr, nullptr);
        else
            k_ff<1><<<NTOK / 32, 128, 0, stream>>>(hbuf, ln2 + bi * D,
                                                   wup + bi * 2 * D * D,
                                                   wdn + bi * D * D,
                                                   nullptr, postw, projw,
                                                   projb, out);
    }
}